// Round 1
// baseline (828.607 us; speedup 1.0000x reference)
//
#include <hip/hip_runtime.h>

#define NROWS   100000
#define DIM     592
#define NINV    128
#define NEQ     112
#define NCH     240
#define ROWS    64
#define BLK     256
#define HOFF    8192          // float offset of H (LN-output) buffer in lds
#define GRID    ((NROWS + ROWS - 1) / ROWS)

typedef float f32x4 __attribute__((ext_vector_type(4)));

// Quad-swizzle: permute quad index q (16B granules) within aligned 4-quad blocks
// by XOR with the row's group key ((r>>3)&3). Same formula on every write & read.
__device__ __forceinline__ int swz(int q, int r) {
    return (q & ~3) | ((q ^ (r >> 3)) & 3);
}

__global__ __launch_bounds__(BLK, 2)
void evmlp_kernel(const float* __restrict__ ten,
                  const float* __restrict__ w1,
                  const float* __restrict__ g1,
                  const float* __restrict__ be1,
                  const float* __restrict__ w2,
                  const float* __restrict__ b2,
                  const float* __restrict__ g2,
                  const float* __restrict__ be2,
                  const float* __restrict__ w3,
                  const float* __restrict__ b3,
                  float* __restrict__ out)
{
    // Regions (float offsets):
    //   sX: [0, 15360)  = 64 rows x 240, row-major, quad-swizzled (x1)
    //   P : [0, 8192)   = 64 x 128 partial-exchange buffer (aliases sX after GEMM1)
    //   H : [8192,16384)= 64 x 128 LN output (aliases sX tail after GEMM1)
    __shared__ __align__(16) float lds[16384];   // 64 KiB -> 2 blocks/CU

    const int t  = threadIdx.x;
    const int r0 = blockIdx.x * ROWS;

    // ---- preprocess A: x10 (k<128) -> sX, vectorized both sides ----
    #pragma unroll
    for (int it = 0; it < 8; ++it) {
        int i = t + it * BLK;              // 0..2047 quads
        int r = i >> 5, q = i & 31;
        int rd = r0 + r; if (rd >= NROWS) rd = NROWS - 1;   // clamp tail reads
        f32x4 v = *(const f32x4*)(ten + (size_t)rd * DIM + (q << 2));
        *(f32x4*)(lds + r * NCH + (swz(q, r) << 2)) = v;
    }

    // ---- preprocess B: equivariant -> x11 into sX, x2 -> out ----
    for (int i = t; i < ROWS * NEQ; i += BLK) {
        int r = i / NEQ, c = i - r * NEQ;
        int rd = r0 + r; const bool valid = rd < NROWS; if (!valid) rd = NROWS - 1;
        int base, nc;
        if (c < 64)      { base = 3 * c;              nc = 3; }
        else if (c < 96) { base = 192 + 5 * (c - 64); nc = 5; }
        else             { base = 352 + 7 * (c - 96); nc = 7; }
        const float* p = ten + (size_t)rd * DIM + NINV + base;
        float vals[7]; float ssq = 1.0f;
        for (int j = 0; j < nc; ++j) { float v = p[j]; vals[j] = v; ssq += v * v; }
        float dv = sqrtf(ssq), inv = 1.0f / dv;
        int k = NINV + c;
        lds[r * NCH + (swz(k >> 2, r) << 2) + (k & 3)] = dv - 1.0f;
        if (valid) {
            float* po = out + (size_t)rd * DIM + NINV + base;
            for (int j = 0; j < nc; ++j) po[j] = vals[j] * inv;
        }
    }
    __syncthreads();

    // ---- thread geometry: 16 col-groups x 8 row-groups x 2 k-halves ----
    const int cgrp = t & 15;
    const int rgrp = (t >> 4) & 7;
    const int kg   = t >> 7;               // k-split half
    const int rr   = rgrp << 3;            // 8 rows per thread
    const int par  = rgrp & 1;             // w-load dedup rotation
    const int qA   = 2 * cgrp + par;       // col-quad for acc[.][0..3]
    const int qB   = 2 * cgrp + 1 - par;   // col-quad for acc[.][4..7]
    const int colA = qA << 2;
    const int colB = qB << 2;

    float acc[8][8];

    auto zero_acc = [&]() {
        #pragma unroll
        for (int i = 0; i < 8; ++i)
            #pragma unroll
            for (int j = 0; j < 8; ++j) acc[i][j] = 0.f;
    };

    // x from LDS (broadcast, swizzle-conflict-free), w streamed from global (L1).
    auto run_gemm = [&](const float* __restrict__ w, const float* xb, int xstride,
                        int kbase, int kn) {
        #pragma unroll 2
        for (int kc = 0; kc < kn; kc += 4) {
            const int k0 = kbase + kc;
            const int pg = swz(k0 >> 2, rr) << 2;
            f32x4 xv[8];
            #pragma unroll
            for (int i = 0; i < 8; ++i)
                xv[i] = *(const f32x4*)(xb + (rr + i) * xstride + pg);
            #pragma unroll
            for (int kk = 0; kk < 4; ++kk) {
                f32x4 wa = *(const f32x4*)(w + (size_t)(k0 + kk) * NINV + colA);
                f32x4 wb = *(const f32x4*)(w + (size_t)(k0 + kk) * NINV + colB);
                #pragma unroll
                for (int i = 0; i < 8; ++i) {
                    const float x = xv[i][kk];
                    acc[i][0] += x * wa[0]; acc[i][1] += x * wa[1];
                    acc[i][2] += x * wa[2]; acc[i][3] += x * wa[3];
                    acc[i][4] += x * wb[0]; acc[i][5] += x * wb[1];
                    acc[i][6] += x * wb[2]; acc[i][7] += x * wb[3];
                }
            }
        }
    };

    // write partner's 4 rows of partial sums into P
    auto put_partial = [&]() {
        const int io = 4 * (1 - kg);
        #pragma unroll
        for (int i2 = 0; i2 < 4; ++i2) {
            const int r = rr + io + i2;
            f32x4 a = { acc[io+i2][0], acc[io+i2][1], acc[io+i2][2], acc[io+i2][3] };
            f32x4 b = { acc[io+i2][4], acc[io+i2][5], acc[io+i2][6], acc[io+i2][7] };
            *(f32x4*)(lds + r * NINV + (swz(qA, r) << 2)) = a;
            *(f32x4*)(lds + r * NINV + (swz(qB, r) << 2)) = b;
        }
    };

    // ================= GEMM1: h = x1 @ w1 (K=240, split 120/120) =================
    zero_acc();
    run_gemm(w1, lds, NCH, kg * 120, 120);
    __syncthreads();                       // all GEMM1 reads of sX done (P aliases sX)
    put_partial();
    __syncthreads();                       // P ready
    {   // reduce own 4 rows + LN1 -> H
        const int io = 4 * kg;
        f32x4 ga = *(const f32x4*)(g1 + colA), gb = *(const f32x4*)(g1 + colB);
        f32x4 ba = *(const f32x4*)(be1 + colA), bb = *(const f32x4*)(be1 + colB);
        #pragma unroll
        for (int i2 = 0; i2 < 4; ++i2) {
            const int r = rr + io + i2;
            f32x4 pa = *(const f32x4*)(lds + r * NINV + (swz(qA, r) << 2));
            f32x4 pb = *(const f32x4*)(lds + r * NINV + (swz(qB, r) << 2));
            float v[8];
            #pragma unroll
            for (int j = 0; j < 4; ++j) {
                v[j]     = acc[io+i2][j]     + pa[j];
                v[4 + j] = acc[io+i2][4 + j] + pb[j];
            }
            float s = 0.f, s2 = 0.f;
            #pragma unroll
            for (int j = 0; j < 8; ++j) { s += v[j]; s2 += v[j] * v[j]; }
            #pragma unroll
            for (int off = 1; off < 16; off <<= 1) {
                s  += __shfl_xor(s,  off);
                s2 += __shfl_xor(s2, off);
            }
            const float mu   = s * (1.f / 128.f);
            const float rstd = rsqrtf(s2 * (1.f / 128.f) - mu * mu + 1e-5f);
            f32x4 ha, hb;
            #pragma unroll
            for (int j = 0; j < 4; ++j) {
                ha[j] = (v[j]     - mu) * rstd * ga[j] + ba[j];
                hb[j] = (v[4 + j] - mu) * rstd * gb[j] + bb[j];
            }
            *(f32x4*)(lds + HOFF + r * NINV + (swz(qA, r) << 2)) = ha;
            *(f32x4*)(lds + HOFF + r * NINV + (swz(qB, r) << 2)) = hb;
        }
    }
    __syncthreads();                       // H ready

    // ================= GEMM2: h@w2 + b2, silu, LN2 (K=128, split 64/64) ==========
    zero_acc();
    run_gemm(w2, lds + HOFF, NINV, kg * 64, 64);
    put_partial();                         // P disjoint from H: no pre-barrier needed
    __syncthreads();                       // P ready AND all GEMM2 H-reads done
    {
        const int io = 4 * kg;
        f32x4 ga  = *(const f32x4*)(g2 + colA),  gb  = *(const f32x4*)(g2 + colB);
        f32x4 ba  = *(const f32x4*)(be2 + colA), bb  = *(const f32x4*)(be2 + colB);
        f32x4 b2a = *(const f32x4*)(b2 + colA),  b2b = *(const f32x4*)(b2 + colB);
        #pragma unroll
        for (int i2 = 0; i2 < 4; ++i2) {
            const int r = rr + io + i2;
            f32x4 pa = *(const f32x4*)(lds + r * NINV + (swz(qA, r) << 2));
            f32x4 pb = *(const f32x4*)(lds + r * NINV + (swz(qB, r) << 2));
            float v[8];
            #pragma unroll
            for (int j = 0; j < 4; ++j) {
                float x0 = acc[io+i2][j]     + pa[j] + b2a[j];
                float x1 = acc[io+i2][4 + j] + pb[j] + b2b[j];
                v[j]     = x0 / (1.f + __expf(-x0));   // silu
                v[4 + j] = x1 / (1.f + __expf(-x1));
            }
            float s = 0.f, s2 = 0.f;
            #pragma unroll
            for (int j = 0; j < 8; ++j) { s += v[j]; s2 += v[j] * v[j]; }
            #pragma unroll
            for (int off = 1; off < 16; off <<= 1) {
                s  += __shfl_xor(s,  off);
                s2 += __shfl_xor(s2, off);
            }
            const float mu   = s * (1.f / 128.f);
            const float rstd = rsqrtf(s2 * (1.f / 128.f) - mu * mu + 1e-5f);
            f32x4 ha, hb;
            #pragma unroll
            for (int j = 0; j < 4; ++j) {
                ha[j] = (v[j]     - mu) * rstd * ga[j] + ba[j];
                hb[j] = (v[4 + j] - mu) * rstd * gb[j] + bb[j];
            }
            *(f32x4*)(lds + HOFF + r * NINV + (swz(qA, r) << 2)) = ha;
            *(f32x4*)(lds + HOFF + r * NINV + (swz(qB, r) << 2)) = hb;
        }
    }
    __syncthreads();                       // H ready

    // ================= GEMM3: h@w3 + b3 -> out[:, 0:128] =========================
    zero_acc();
    run_gemm(w3, lds + HOFF, NINV, kg * 64, 64);
    put_partial();
    __syncthreads();                       // P ready
    {
        const int io = 4 * kg;
        f32x4 b3a = *(const f32x4*)(b3 + colA), b3b = *(const f32x4*)(b3 + colB);
        #pragma unroll
        for (int i2 = 0; i2 < 4; ++i2) {
            const int r  = rr + io + i2;
            const int rd = r0 + r;
            f32x4 pa = *(const f32x4*)(lds + r * NINV + (swz(qA, r) << 2));
            f32x4 pb = *(const f32x4*)(lds + r * NINV + (swz(qB, r) << 2));
            f32x4 oa, ob;
            #pragma unroll
            for (int j = 0; j < 4; ++j) {
                oa[j] = acc[io+i2][j]     + pa[j] + b3a[j];
                ob[j] = acc[io+i2][4 + j] + pb[j] + b3b[j];
            }
            if (rd < NROWS) {
                *(f32x4*)(out + (size_t)rd * DIM + colA) = oa;
                *(f32x4*)(out + (size_t)rd * DIM + colB) = ob;
            }
        }
    }
}

extern "C" void kernel_launch(void* const* d_in, const int* in_sizes, int n_in,
                              void* d_out, int out_size, void* d_ws, size_t ws_size,
                              hipStream_t stream) {
    const float* ten = (const float*)d_in[0];
    // d_in[1] = rep_layout (integer) — layout is compile-time known, unused
    const float* w1  = (const float*)d_in[2];
    const float* g1  = (const float*)d_in[3];
    const float* be1 = (const float*)d_in[4];
    const float* w2  = (const float*)d_in[5];
    const float* b2  = (const float*)d_in[6];
    const float* g2  = (const float*)d_in[7];
    const float* be2 = (const float*)d_in[8];
    const float* w3  = (const float*)d_in[9];
    const float* b3  = (const float*)d_in[10];
    float* out = (float*)d_out;

    dim3 grid(GRID);   // 1563
    dim3 block(BLK);
    evmlp_kernel<<<grid, block, 0, stream>>>(ten, w1, g1, be1, w2, b2, g2, be2, w3, b3, out);
}

// Round 2
// 815.704 us; speedup vs baseline: 1.0158x; 1.0158x over previous
//
#include <hip/hip_runtime.h>

#define NROWS   100000
#define DIM     592
#define NINV    128
#define NEQ     112
#define NCH     240
#define ROWS    32
#define BLK     256
#define LDSF    8192        // floats. x:[0,7680)  H:[0,4096)  P:[4096,8192)
#define POFF    4096
#define GRID    (NROWS / ROWS)   // 3125 exact

typedef float f32x4 __attribute__((ext_vector_type(4)));

// Quad-swizzle: permute quad index q (16B granules) within aligned 4-quad blocks
// by XOR with the row's 8-row-group key. Same formula on every write & read.
__device__ __forceinline__ int swz(int q, int r) {
    return (q & ~3) | ((q ^ (r >> 3)) & 3);
}

__global__ __launch_bounds__(BLK, 4)
void evmlp_kernel(const float* __restrict__ ten,
                  const float* __restrict__ w1,
                  const float* __restrict__ g1,
                  const float* __restrict__ be1,
                  const float* __restrict__ w2,
                  const float* __restrict__ b2,
                  const float* __restrict__ g2,
                  const float* __restrict__ be2,
                  const float* __restrict__ w3,
                  const float* __restrict__ b3,
                  float* __restrict__ out)
{
    __shared__ __align__(16) float lds[LDSF];   // 32 KiB -> 4-5 blocks/CU

    const int t  = threadIdx.x;
    const int r0 = blockIdx.x * ROWS;

    // ---- preprocess A: x10 (cols 0..127) -> x, vectorized both sides ----
    #pragma unroll
    for (int it = 0; it < 4; ++it) {
        int i = t + it * BLK;              // 0..1023 quads (32 rows x 32 quads)
        int r = i >> 5, q = i & 31;
        f32x4 v = *(const f32x4*)(ten + (size_t)(r0 + r) * DIM + (q << 2));
        *(f32x4*)(lds + r * NCH + (swz(q, r) << 2)) = v;
    }

    // ---- preprocess B: equivariant -> x11 into x, x2 -> out ----
    for (int i = t; i < ROWS * NEQ; i += BLK) {
        int r = i / NEQ, c = i - r * NEQ;
        int base, nc;
        if (c < 64)      { base = 3 * c;              nc = 3; }
        else if (c < 96) { base = 192 + 5 * (c - 64); nc = 5; }
        else             { base = 352 + 7 * (c - 96); nc = 7; }
        const float* p = ten + (size_t)(r0 + r) * DIM + NINV + base;
        float vals[7]; float ssq = 1.0f;
        for (int j = 0; j < nc; ++j) { float v = p[j]; vals[j] = v; ssq += v * v; }
        float dv = sqrtf(ssq), inv = 1.0f / dv;
        int k = NINV + c;
        lds[r * NCH + (swz(k >> 2, r) << 2) + (k & 3)] = dv - 1.0f;
        float* po = out + (size_t)(r0 + r) * DIM + NINV + base;
        for (int j = 0; j < nc; ++j) po[j] = vals[j] * inv;
    }
    __syncthreads();

    // ---- thread geometry: 32 col-groups x 4 row-groups x 2 k-halves ----
    const int cgrp = t & 31;               // quad column (4 cols)
    const int rgrp = (t >> 5) & 3;         // 8-row group
    const int kg   = t >> 7;               // k-split half
    const int rr   = rgrp << 3;
    const int c0   = cgrp << 2;

    float acc[8][4];

    auto zero_acc = [&]() {
        #pragma unroll
        for (int i = 0; i < 8; ++i)
            #pragma unroll
            for (int j = 0; j < 4; ++j) acc[i][j] = 0.f;
    };

    // x from LDS (broadcast, swizzle-consistent), w streamed from global (L1/L2).
    auto run_gemm = [&](const float* __restrict__ w, const float* xb, int xstride,
                        int kbase, int kn) {
        for (int kc = 0; kc < kn; kc += 4) {
            const int k0 = kbase + kc;
            const int pg = swz(k0 >> 2, rr) << 2;
            f32x4 xv[8];
            #pragma unroll
            for (int i = 0; i < 8; ++i)
                xv[i] = *(const f32x4*)(xb + (rr + i) * xstride + pg);
            f32x4 wv[4];
            #pragma unroll
            for (int kk = 0; kk < 4; ++kk)
                wv[kk] = *(const f32x4*)(w + (size_t)(k0 + kk) * NINV + c0);
            #pragma unroll
            for (int kk = 0; kk < 4; ++kk)
                #pragma unroll
                for (int i = 0; i < 8; ++i) {
                    const float x = xv[i][kk];
                    acc[i][0] += x * wv[kk][0];
                    acc[i][1] += x * wv[kk][1];
                    acc[i][2] += x * wv[kk][2];
                    acc[i][3] += x * wv[kk][3];
                }
        }
    };

    // write partner's 4 rows of partial sums into P
    auto put_partial = [&]() {
        const int io = 4 * (1 - kg);
        #pragma unroll
        for (int i2 = 0; i2 < 4; ++i2) {
            const int r = rr + io + i2;
            f32x4 a = { acc[io + i2][0], acc[io + i2][1],
                        acc[io + i2][2], acc[io + i2][3] };
            *(f32x4*)(lds + POFF + r * NINV + (swz(cgrp, r) << 2)) = a;
        }
    };

    // ================= GEMM1: h = x1 @ w1 (K=240, split 120/120) =================
    zero_acc();
    run_gemm(w1, lds, NCH, kg * 120, 120);
    __syncthreads();                       // all GEMM1 x-reads done (P aliases x tail)
    put_partial();
    __syncthreads();                       // P ready
    {   // reduce own 4 rows + LN1 -> H (aliases x head; disjoint from P)
        const int io = 4 * kg;
        f32x4 gv = *(const f32x4*)(g1 + c0);
        f32x4 bv = *(const f32x4*)(be1 + c0);
        #pragma unroll
        for (int i2 = 0; i2 < 4; ++i2) {
            const int r = rr + io + i2;
            f32x4 pv = *(const f32x4*)(lds + POFF + r * NINV + (swz(cgrp, r) << 2));
            float v[4];
            #pragma unroll
            for (int j = 0; j < 4; ++j) v[j] = acc[io + i2][j] + pv[j];
            float s = 0.f, s2 = 0.f;
            #pragma unroll
            for (int j = 0; j < 4; ++j) { s += v[j]; s2 += v[j] * v[j]; }
            #pragma unroll
            for (int off = 1; off < 32; off <<= 1) {
                s  += __shfl_xor(s,  off);
                s2 += __shfl_xor(s2, off);
            }
            const float mu   = s * (1.f / 128.f);
            const float rstd = rsqrtf(s2 * (1.f / 128.f) - mu * mu + 1e-5f);
            f32x4 h;
            #pragma unroll
            for (int j = 0; j < 4; ++j) h[j] = (v[j] - mu) * rstd * gv[j] + bv[j];
            *(f32x4*)(lds + r * NINV + (swz(cgrp, r) << 2)) = h;
        }
    }
    __syncthreads();                       // H ready

    // ================= GEMM2: h@w2 + b2, silu, LN2 (K=128, split 64/64) ==========
    zero_acc();
    run_gemm(w2, lds, NINV, kg * 64, 64);
    put_partial();                         // P disjoint from H: no pre-barrier needed
    __syncthreads();                       // P ready AND all GEMM2 H-reads done
    {
        const int io = 4 * kg;
        f32x4 gv  = *(const f32x4*)(g2 + c0);
        f32x4 bv  = *(const f32x4*)(be2 + c0);
        f32x4 b2v = *(const f32x4*)(b2 + c0);
        #pragma unroll
        for (int i2 = 0; i2 < 4; ++i2) {
            const int r = rr + io + i2;
            f32x4 pv = *(const f32x4*)(lds + POFF + r * NINV + (swz(cgrp, r) << 2));
            float v[4];
            #pragma unroll
            for (int j = 0; j < 4; ++j) {
                float x0 = acc[io + i2][j] + pv[j] + b2v[j];
                v[j] = x0 / (1.f + __expf(-x0));    // silu
            }
            float s = 0.f, s2 = 0.f;
            #pragma unroll
            for (int j = 0; j < 4; ++j) { s += v[j]; s2 += v[j] * v[j]; }
            #pragma unroll
            for (int off = 1; off < 32; off <<= 1) {
                s  += __shfl_xor(s,  off);
                s2 += __shfl_xor(s2, off);
            }
            const float mu   = s * (1.f / 128.f);
            const float rstd = rsqrtf(s2 * (1.f / 128.f) - mu * mu + 1e-5f);
            f32x4 h;
            #pragma unroll
            for (int j = 0; j < 4; ++j) h[j] = (v[j] - mu) * rstd * gv[j] + bv[j];
            *(f32x4*)(lds + r * NINV + (swz(cgrp, r) << 2)) = h;
        }
    }
    __syncthreads();                       // H ready

    // ================= GEMM3: h@w3 + b3 -> out[:, 0:128] =========================
    zero_acc();
    run_gemm(w3, lds, NINV, kg * 64, 64);
    put_partial();
    __syncthreads();                       // P ready
    {
        const int io = 4 * kg;
        f32x4 b3v = *(const f32x4*)(b3 + c0);
        #pragma unroll
        for (int i2 = 0; i2 < 4; ++i2) {
            const int r = rr + io + i2;
            f32x4 pv = *(const f32x4*)(lds + POFF + r * NINV + (swz(cgrp, r) << 2));
            f32x4 o;
            #pragma unroll
            for (int j = 0; j < 4; ++j) o[j] = acc[io + i2][j] + pv[j] + b3v[j];
            *(f32x4*)(out + (size_t)(r0 + r) * DIM + c0) = o;
        }
    }
}

extern "C" void kernel_launch(void* const* d_in, const int* in_sizes, int n_in,
                              void* d_out, int out_size, void* d_ws, size_t ws_size,
                              hipStream_t stream) {
    const float* ten = (const float*)d_in[0];
    // d_in[1] = rep_layout (integer) — layout is compile-time known, unused
    const float* w1  = (const float*)d_in[2];
    const float* g1  = (const float*)d_in[3];
    const float* be1 = (const float*)d_in[4];
    const float* w2  = (const float*)d_in[5];
    const float* b2  = (const float*)d_in[6];
    const float* g2  = (const float*)d_in[7];
    const float* be2 = (const float*)d_in[8];
    const float* w3  = (const float*)d_in[9];
    const float* b3  = (const float*)d_in[10];
    float* out = (float*)d_out;

    dim3 grid(GRID);   // 3125
    dim3 block(BLK);
    evmlp_kernel<<<grid, block, 0, stream>>>(ten, w1, g1, be1, w2, b2, g2, be2, w3, b3, out);
}